// Round 8
// baseline (429.259 us; speedup 1.0000x reference)
//
#include <hip/hip_runtime.h>
#include <cstdint>
#include <cstddef>

#define BETA 5.5f
#define ALPHA 0.5f

constexpr int D   = 512;     // feature dim
constexpr int NB  = 4096;    // queries
constexpr int NK  = 16384;   // keys
constexpr int BQ  = 32;      // query tile per block
constexpr int BN  = 32;      // key chunk
constexpr int NSPLIT = 8;    // nsplit == XCD id under round-robin -> 4MB L2 slice
constexpr int NRANGE = NK / NSPLIT;   // 2048
constexpr int CHUNKS = NRANGE / BN;   // 64
constexpr int KROW = D + 8;           // padded LDS row (bf16), 1040 B (16B mult)
constexpr int PROW = BN + 8;          // padded P row: 40

typedef __attribute__((ext_vector_type(8)))  short    short8;
typedef __attribute__((ext_vector_type(4)))  float    floatx4;
typedef __attribute__((ext_vector_type(4)))  uint32_t uint4v;
typedef __attribute__((ext_vector_type(2)))  uint32_t uint2v;

__device__ inline uint32_t f2bf1(float f) {
  union { float f; uint32_t u; } v; v.f = f;
  return (v.u + 0x7FFFu + ((v.u >> 16) & 1u)) >> 16;   // RNE
}
__device__ inline uint32_t pack2(float a, float b) {
  return f2bf1(a) | (f2bf1(b) << 16);
}

__device__ inline void load_lds16(const void* g, void* l) {
  __builtin_amdgcn_global_load_lds(
      (const __attribute__((address_space(1))) uint32_t*)g,
      (__attribute__((address_space(3))) uint32_t*)l, 16, 0, 0);
}

// ---------------- normalize Q -> Qn (bf16), and init out = Q ----------------
__global__ void norm_q_kernel(const float* __restrict__ q,
                              float* __restrict__ out,
                              unsigned short* __restrict__ Qn) {
  const int wave = threadIdx.x >> 6, lane = threadIdx.x & 63;
  const int row = blockIdx.x * 4 + wave;
  const float4* qr = (const float4*)(q + (size_t)row * D);
  float4 a = qr[lane * 2];
  float4 b = qr[lane * 2 + 1];
  float ss = a.x*a.x + a.y*a.y + a.z*a.z + a.w*a.w
           + b.x*b.x + b.y*b.y + b.z*b.z + b.w*b.w;
#pragma unroll
  for (int m = 32; m >= 1; m >>= 1) ss += __shfl_xor(ss, m, 64);
  const float sc = 1.0f / fmaxf(sqrtf(ss), 1e-12f);
  float4* orow = (float4*)(out + (size_t)row * D);
  orow[lane * 2]     = a;
  orow[lane * 2 + 1] = b;
  uint4v w;
  w.x = pack2(a.x*sc, a.y*sc); w.y = pack2(a.z*sc, a.w*sc);
  w.z = pack2(b.x*sc, b.y*sc); w.w = pack2(b.z*sc, b.w*sc);
  *(uint4v*)(Qn + (size_t)row * D + lane * 8) = w;
}

// ------ normalize K -> Kn (bf16 row-major) + KnT (bf16 transposed) ----------
__global__ void norm_k_kernel(const float* __restrict__ k,
                              unsigned short* __restrict__ Kn,
                              unsigned short* __restrict__ KnT) {
  __shared__ unsigned short tile[64 * KROW];
  const int wave = threadIdx.x >> 6, lane = threadIdx.x & 63;
  const int n0 = blockIdx.x * 64;
#pragma unroll
  for (int i = 0; i < 4; ++i) {
    const int rl = wave * 4 + i;
    const int n  = n0 + rl;
    const float4* kr = (const float4*)(k + (size_t)n * D);
    float4 a = kr[lane * 2], b = kr[lane * 2 + 1];
    float ss = a.x*a.x + a.y*a.y + a.z*a.z + a.w*a.w
             + b.x*b.x + b.y*b.y + b.z*b.z + b.w*b.w;
#pragma unroll
    for (int m = 32; m >= 1; m >>= 1) ss += __shfl_xor(ss, m, 64);
    const float sc = 1.0f / fmaxf(sqrtf(ss), 1e-12f);
    uint4v w;
    w.x = pack2(a.x*sc, a.y*sc); w.y = pack2(a.z*sc, a.w*sc);
    w.z = pack2(b.x*sc, b.y*sc); w.w = pack2(b.z*sc, b.w*sc);
    *(uint4v*)(Kn + (size_t)n * D + lane * 8) = w;
    *(uint4v*)&tile[rl * KROW + lane * 8]     = w;
  }
  __syncthreads();
  const int dsub = threadIdx.x >> 3;        // 0..127
  const int nl   = (threadIdx.x & 7) * 8;   // 0..56
#pragma unroll
  for (int iter = 0; iter < 4; ++iter) {
    const int d = iter * 128 + dsub;
    uint4v w;
    w.x = (uint32_t)tile[(nl+0)*KROW + d] | ((uint32_t)tile[(nl+1)*KROW + d] << 16);
    w.y = (uint32_t)tile[(nl+2)*KROW + d] | ((uint32_t)tile[(nl+3)*KROW + d] << 16);
    w.z = (uint32_t)tile[(nl+4)*KROW + d] | ((uint32_t)tile[(nl+5)*KROW + d] << 16);
    w.w = (uint32_t)tile[(nl+6)*KROW + d] | ((uint32_t)tile[(nl+7)*KROW + d] << 16);
    *(uint4v*)(KnT + (size_t)d * NK + n0 + nl) = w;
  }
}

// ---------------- fused: S = Qn Kn^T chunk, P = exp, O += P Kn --------------
// OCCUPANCY build: BQ=32/BN=32, LDS 42.5KB, regs<=128 -> 2 blocks/CU
// (4 waves/SIMD). Barrier stalls in one block are covered by the other.
// Roles: wave = (qt, nh, kh): GEMM1 tile (nh,qt) over D-half kh, Sred-reduced.
__global__ __launch_bounds__(512, 4) void fused_kernel(
    const unsigned short* __restrict__ Qn,
    const unsigned short* __restrict__ Kn,
    const unsigned short* __restrict__ KnT,
    float* __restrict__ out) {
  __shared__ unsigned short K_lds[BN * KROW];      // 33280 B (single buffer)
  __shared__ unsigned short P_lds[2][BQ * PROW];   //  5120 B (double buffer)
  __shared__ float Sred[4][16 * 16];               //  4096 B    total 42.5 KB

  const int tid  = threadIdx.x;
  const int wave = tid >> 6, lane = tid & 63;
  const int l15  = lane & 15, quad = lane >> 4;
  const int nsplit = blockIdx.x & (NSPLIT - 1);
  const int qidx   = blockIdx.x >> 3;           // 0..127
  const int q0     = qidx * BQ;
  const int nbase  = nsplit * NRANGE;
  const int qt = wave & 1, nh = (wave >> 1) & 1, kh = wave >> 2;
  const int g1tile = nh * 2 + qt;

  // GEMM1 B-frags (Q, this wave's kh D-half): loaded ONCE from global (32 VGPR)
  short8 qfB[8];
  {
    const unsigned short* qrow = Qn + (size_t)(q0 + qt*16 + l15) * D
                                 + kh * 256 + quad * 8;
#pragma unroll
    for (int ks = 0; ks < 8; ++ks) qfB[ks] = *(const short8*)(qrow + ks * 32);
  }

  floatx4 oacc[2][4] = {};   // O slice: q (2 tr-tiles) x d (wave*64, 4 td) = 32
  short8  ktf[4];            // GEMM2 B-frags (16 VGPR)

  // prologue: stage chunk 0 (kh=1 waves), load ktf(0)
  if (kh == 1) {
    const int widx = wave - 4;
#pragma unroll
    for (int i = 0; i < 8; ++i) {
      const int row = widx * 8 + i;
      load_lds16(Kn + (size_t)(nbase + row) * D + lane * 8, &K_lds[row * KROW]);
    }
  }
#pragma unroll
  for (int td = 0; td < 4; ++td)
    ktf[td] = *(const short8*)(KnT + (size_t)(wave*64 + td*16 + l15) * NK
                               + (nbase + quad*8));
  __syncthreads();   // chunk-0 staging drained

#pragma unroll 1
  for (int c = 0; c < CHUNKS; ++c) {
    const int cur = c & 1;
    const int cn = (c + 1 < CHUNKS) ? c + 1 : c;

    // ---- GEMM1: tile (nh,qt), D-half kh. A from K_lds, B = qfB regs.
    floatx4 s = {};
    {
      const unsigned short* abase = &K_lds[(nh*16 + l15) * KROW + kh*256 + quad*8];
#pragma unroll
      for (int ks = 0; ks < 8; ++ks) {
        short8 a = *(const short8*)(abase + ks * 32);
        s = __builtin_amdgcn_mfma_f32_16x16x32_bf16(a, qfB[ks], s, 0, 0, 0);
      }
    }
    if (kh == 1) {                       // export partial S
      float* sr = &Sred[g1tile][lane * 4];
      *(float4*)sr = *(float4*)&s;
    }
    __syncthreads();   // bar-A: Sred visible; all K_lds(c) reads complete

    if (kh == 1) {                       // stage chunk c+1 (overwrites K_lds)
      if (c + 1 < CHUNKS) {
        const int widx = wave - 4;
#pragma unroll
        for (int i = 0; i < 8; ++i) {
          const int row = widx * 8 + i;
          load_lds16(Kn + (size_t)(nbase + (c+1)*BN + row) * D + lane * 8,
                     &K_lds[row * KROW]);
        }
      }
    } else {                             // kh=0: reduce, exp, write P
      float4 r = *(const float4*)&Sred[g1tile][lane * 4];
      float e0 = __expf(BETA * (s[0] + r.x - 1.f));
      float e1 = __expf(BETA * (s[1] + r.y - 1.f));
      float e2 = __expf(BETA * (s[2] + r.z - 1.f));
      float e3 = __expf(BETA * (s[3] + r.w - 1.f));
      uint2v w; w.x = pack2(e0, e1); w.y = pack2(e2, e3);
      // P[q][key]: q = qt*16+l15, keys nh*16 + quad*4 + {0..3}
      *(uint2v*)&P_lds[cur][(qt*16 + l15) * PROW + nh*16 + quad*4] = w;
    }
    __syncthreads();   // bar-B: P(c) visible; staging(c+1) drained

    // ---- GEMM2: O += P (LDS, A-op) * ktf (regs, B-op); k = 32 (one step)
#pragma unroll
    for (int tr = 0; tr < 2; ++tr) {
      short8 pf = *(const short8*)&P_lds[cur][(tr*16 + l15) * PROW + quad*8];
#pragma unroll
      for (int td = 0; td < 4; ++td)
        oacc[tr][td] = __builtin_amdgcn_mfma_f32_16x16x32_bf16(
            pf, ktf[td], oacc[tr][td], 0, 0, 0);
    }

    // ---- load next chunk's ktf (WAR after use; drained by bar-A/B of c+1)
#pragma unroll
    for (int td = 0; td < 4; ++td)
      ktf[td] = *(const short8*)(KnT + (size_t)(wave*64 + td*16 + l15) * NK
                                 + (nbase + cn*BN + quad*8));
  }

  // ---- epilogue: out += ALPHA * O (out pre-init to Q; atomics L2-coalesce)
#pragma unroll
  for (int tr = 0; tr < 2; ++tr)
#pragma unroll
    for (int td = 0; td < 4; ++td)
#pragma unroll
      for (int r = 0; r < 4; ++r)
        atomicAdd(out + (size_t)(q0 + tr*16 + quad*4 + r) * D
                      + wave*64 + td*16 + l15,
                  ALPHA * oacc[tr][td][r]);
}

extern "C" void kernel_launch(void* const* d_in, const int* in_sizes, int n_in,
                              void* d_out, int out_size, void* d_ws, size_t ws_size,
                              hipStream_t stream) {
  (void)in_sizes; (void)n_in; (void)out_size; (void)ws_size;
  const float* q = (const float*)d_in[0];
  const float* k = (const float*)d_in[1];
  float* out = (float*)d_out;
  unsigned short* Qn  = (unsigned short*)d_ws;          //  4 MB
  unsigned short* Kn  = Qn + (size_t)NB * D;            // 16 MB
  unsigned short* KnT = Kn + (size_t)NK * D;            // 16 MB  (total 36 MB)

  hipLaunchKernelGGL(norm_q_kernel, dim3(NB / 4),  dim3(256),  0, stream, q, out, Qn);
  hipLaunchKernelGGL(norm_k_kernel, dim3(NK / 64), dim3(1024), 0, stream, k, Kn, KnT);
  hipLaunchKernelGGL(fused_kernel, dim3((NB / BQ) * NSPLIT), dim3(512), 0, stream,
                     Qn, Kn, KnT, out);
}